// Round 2
// baseline (770.584 us; speedup 1.0000x reference)
//
#include <hip/hip_runtime.h>
#include <hip/hip_bf16.h>
#include <math.h>

// ---------------------------------------------------------------------------
// ToyMoE: top-1 routed 2-expert MLP. H=2048, tokens = 4*2048 = 8192.
//   gate: fp64 dot (exactness for argmax routing)
//   experts: bf16 MFMA GEMMs (tolerance is bf16-level), only the selected
//   expert is computed per token (half the reference FLOPs).
// ---------------------------------------------------------------------------

#define HDIM   2048
#define TOKENS 8192
#define FDIM   4096   // 2*H

typedef __bf16 bf16x8 __attribute__((ext_vector_type(8)));
typedef float  f32x4  __attribute__((ext_vector_type(4)));

// workspace layout (bytes)
#define CNT_OFF  0           // n0 (int), n1 (int)
#define PERM_OFF 256         // int[8192]
#define XG_OFF   65536       // bf16 [8192][2048]   = 33554432 B
#define WA_OFF   33619968    // bf16 [2][4096][2048] = 33554432 B
#define WB_OFF   67174400    // bf16 [2][2048][4096] = 33554432 B
#define HB_OFF   100728832   // bf16 [8192][4096]    = 67108864 B
// total = 167837696 B (~160 MiB)

typedef __attribute__((address_space(1))) const unsigned int as1_u32;
typedef __attribute__((address_space(3))) unsigned int       as3_u32;

__device__ __forceinline__ void gl2lds16(const void* g, void* l) {
    // C-style casts lower to addrspacecast (reinterpret_cast is rejected).
    __builtin_amdgcn_global_load_lds((as1_u32*)g, (as3_u32*)l, 16, 0, 0);
}

// ---------------- gate: fp64 logits, argmax routing, build permutation ------
__global__ void moe_gate(const float* __restrict__ x, const float* __restrict__ Wg,
                         int* __restrict__ n0, int* __restrict__ n1,
                         int* __restrict__ perm) {
    __shared__ double r0[256];
    __shared__ double r1[256];
    const int token = blockIdx.x;
    const int tid = threadIdx.x;
    const float* xr = x + (size_t)token * HDIM;
    double s0 = 0.0, s1 = 0.0;
    for (int i = tid; i < HDIM; i += 256) {
        double xv = (double)xr[i];
        s0 += xv * (double)Wg[i];
        s1 += xv * (double)Wg[HDIM + i];
    }
    r0[tid] = s0; r1[tid] = s1;
    __syncthreads();
    for (int off = 128; off > 0; off >>= 1) {
        if (tid < off) { r0[tid] += r0[tid + off]; r1[tid] += r1[tid + off]; }
        __syncthreads();
    }
    if (tid == 0) {
        // softmax is monotone; argmax picks first max => expert1 only if s1 > s0
        if (r1[0] > r0[0]) {
            int p = atomicAdd(n1, 1);
            perm[TOKENS - 1 - p] = token;   // expert1 tokens fill [n0, 8192)
        } else {
            int p = atomicAdd(n0, 1);
            perm[p] = token;                // expert0 tokens fill [0, n0)
        }
    }
}

// ---------------- gather routed tokens, cast fp32 -> bf16 -------------------
__global__ void moe_gather(const float* __restrict__ x, const int* __restrict__ perm,
                           __bf16* __restrict__ Xg) {
    const int r = blockIdx.x;
    const int token = perm[r];
    const float* src = x + (size_t)token * HDIM;
    __bf16* dst = Xg + (size_t)r * HDIM;
    const int i = threadIdx.x * 8;
    float4 a = *reinterpret_cast<const float4*>(src + i);
    float4 b = *reinterpret_cast<const float4*>(src + i + 4);
    bf16x8 v;
    v[0] = (__bf16)a.x; v[1] = (__bf16)a.y; v[2] = (__bf16)a.z; v[3] = (__bf16)a.w;
    v[4] = (__bf16)b.x; v[5] = (__bf16)b.y; v[6] = (__bf16)b.z; v[7] = (__bf16)b.w;
    *reinterpret_cast<bf16x8*>(dst + i) = v;
}

// ---------------- cast the 4 expert weight matrices to bf16 -----------------
__global__ void moe_cast_w(const float* __restrict__ W0a, const float* __restrict__ W1a,
                           const float* __restrict__ W0b, const float* __restrict__ W1b,
                           __bf16* __restrict__ Wa, __bf16* __restrict__ Wb) {
    const int slice = blockIdx.y;  // 0:W0a 1:W1a 2:W0b 3:W1b
    const float* src;
    __bf16* dst;
    const size_t MS = (size_t)FDIM * HDIM;  // 8388608 elements each
    if      (slice == 0) { src = W0a; dst = Wa; }
    else if (slice == 1) { src = W1a; dst = Wa + MS; }
    else if (slice == 2) { src = W0b; dst = Wb; }
    else                 { src = W1b; dst = Wb + MS; }
    const size_t idx = ((size_t)blockIdx.x * 256 + threadIdx.x) * 8;
    float4 a = *reinterpret_cast<const float4*>(src + idx);
    float4 b = *reinterpret_cast<const float4*>(src + idx + 4);
    bf16x8 v;
    v[0] = (__bf16)a.x; v[1] = (__bf16)a.y; v[2] = (__bf16)a.z; v[3] = (__bf16)a.w;
    v[4] = (__bf16)b.x; v[5] = (__bf16)b.y; v[6] = (__bf16)b.z; v[7] = (__bf16)b.w;
    *reinterpret_cast<bf16x8*>(dst + idx) = v;
}

// ---------------- MFMA GEMM, 128x128 tile, BK=32, m97 structure -------------
// A:[8192][KDIM] bf16 (row-major), Bw:[2][NDIM][KDIM] bf16 (K-contiguous, B^T GEMM)
// DOWN=false: out = act(A*B^T + bias) -> Hb bf16 [8192][NDIM]
// DOWN=true : out = A*B^T + bias, scattered fp32 -> Out[perm[row]*2048 + col]
template <int KDIM, int NDIM, bool DOWN>
__global__ void moe_gemm(const __bf16* __restrict__ A, const __bf16* __restrict__ Bw,
                         const float* __restrict__ bias0, const float* __restrict__ bias1,
                         __bf16* __restrict__ Hb, float* __restrict__ Out,
                         const int* __restrict__ n0_ptr, const int* __restrict__ perm) {
    const int e  = blockIdx.z;
    const int n0 = *n0_ptr;
    const int row_lo = e ? n0 : 0;
    const int row_hi = e ? TOKENS : n0;
    const int bm = blockIdx.y * 128;
    if (bm >= row_hi || bm + 128 <= row_lo) return;   // tile outside this expert
    const int bn = blockIdx.x * 128;

    __shared__ __bf16 As[128 * 32];
    __shared__ __bf16 Bs[128 * 32];

    const int tid  = threadIdx.x;
    const int wid  = tid >> 6;
    const int lane = tid & 63;

    const __bf16* Be   = Bw + (size_t)e * NDIM * KDIM;
    const float*  bias = e ? bias1 : bias0;

    // staging: chunk c in [0,8) covers rows c*16..c*16+15; lane l -> row c*16+l/4,
    // 8 bf16 at kcol (l%4)*8. LDS dest = wave-uniform base + lane*16 (required).
    const int srow0 = wid * 16 + (lane >> 2);
    const int skol  = (lane & 3) * 8;
    const __bf16* gA0 = A  + (size_t)(bm + srow0) * KDIM + skol;
    const __bf16* gA1 = A  + (size_t)(bm + srow0 + 64) * KDIM + skol;
    const __bf16* gB0 = Be + (size_t)(bn + srow0) * KDIM + skol;
    const __bf16* gB1 = Be + (size_t)(bn + srow0 + 64) * KDIM + skol;
    __bf16* lA0 = &As[wid * 512];
    __bf16* lA1 = &As[(wid + 4) * 512];
    __bf16* lB0 = &Bs[wid * 512];
    __bf16* lB1 = &Bs[(wid + 4) * 512];

    // wave -> 64x64 quadrant; 4x4 grid of 16x16x32 MFMA tiles
    const int wrow = (wid >> 1) * 64;
    const int wcol = (wid & 1) * 64;
    const int rm = lane & 15;
    const int q8 = (lane >> 4) * 8;

    f32x4 acc[4][4] = {};

    for (int kt = 0; kt < KDIM; kt += 32) {
        gl2lds16(gA0 + kt, lA0);
        gl2lds16(gA1 + kt, lA1);
        gl2lds16(gB0 + kt, lB0);
        gl2lds16(gB1 + kt, lB1);
        __syncthreads();   // drains vmcnt -> LDS tiles ready

        bf16x8 aF[4], bF[4];
#pragma unroll
        for (int i = 0; i < 4; i++)
            aF[i] = *reinterpret_cast<const bf16x8*>(&As[(wrow + i * 16 + rm) * 32 + q8]);
#pragma unroll
        for (int j = 0; j < 4; j++)
            bF[j] = *reinterpret_cast<const bf16x8*>(&Bs[(wcol + j * 16 + rm) * 32 + q8]);
#pragma unroll
        for (int i = 0; i < 4; i++)
#pragma unroll
            for (int j = 0; j < 4; j++)
                acc[i][j] = __builtin_amdgcn_mfma_f32_16x16x32_bf16(aF[i], bF[j], acc[i][j], 0, 0, 0);
        __syncthreads();   // protect LDS before next-iteration staging
    }

    // epilogue. C/D layout: col = lane&15, row = (lane>>4)*4 + reg  [m89/m91]
    const int q4 = (lane >> 4) * 4;
#pragma unroll
    for (int j = 0; j < 4; j++) {
        const int col = bn + wcol + j * 16 + rm;
        const float bv = bias[col];
#pragma unroll
        for (int i = 0; i < 4; i++) {
            const int rbase = bm + wrow + i * 16 + q4;
#pragma unroll
            for (int r = 0; r < 4; r++) {
                const int row = rbase + r;
                if (row >= row_lo && row < row_hi) {   // this expert's rows only
                    float v = acc[i][j][r] + bv;
                    if (!DOWN) {
                        if (e == 0) v = 0.5f * v * (1.0f + erff(v * 0.70710678118654752f)); // exact GELU
                        else        v = v > 0.0f ? v : 0.0f;                                // ReLU
                        Hb[(size_t)row * NDIM + col] = (__bf16)v;
                    } else {
                        Out[(size_t)perm[row] * HDIM + col] = v;
                    }
                }
            }
        }
    }
}

extern "C" void kernel_launch(void* const* d_in, const int* in_sizes, int n_in,
                              void* d_out, int out_size, void* d_ws, size_t ws_size,
                              hipStream_t stream) {
    const float* x   = (const float*)d_in[0];
    const float* Wg  = (const float*)d_in[1];
    const float* W0a = (const float*)d_in[2];
    const float* b0a = (const float*)d_in[3];
    const float* W0b = (const float*)d_in[4];
    const float* b0b = (const float*)d_in[5];
    const float* W1a = (const float*)d_in[6];
    const float* b1a = (const float*)d_in[7];
    const float* W1b = (const float*)d_in[8];
    const float* b1b = (const float*)d_in[9];
    float* out = (float*)d_out;

    char* w = (char*)d_ws;
    int* n0   = (int*)(w + CNT_OFF);
    int* n1   = n0 + 1;
    int* perm = (int*)(w + PERM_OFF);
    __bf16* Xg = (__bf16*)(w + XG_OFF);
    __bf16* Wa = (__bf16*)(w + WA_OFF);
    __bf16* Wb = (__bf16*)(w + WB_OFF);
    __bf16* Hb = (__bf16*)(w + HB_OFF);

    (void)hipMemsetAsync(w, 0, 256, stream);
    moe_gate<<<TOKENS, 256, 0, stream>>>(x, Wg, n0, n1, perm);
    moe_gather<<<TOKENS, 256, 0, stream>>>(x, perm, Xg);
    moe_cast_w<<<dim3(4096, 4), 256, 0, stream>>>(W0a, W1a, W0b, W1b, Wa, Wb);
    // up: M=8192(route-split) K=2048 N=4096, fused bias+act, bf16 out
    moe_gemm<HDIM, FDIM, false><<<dim3(FDIM / 128, TOKENS / 128, 2), 256, 0, stream>>>(
        Xg, Wa, b0a, b1a, Hb, nullptr, n0, perm);
    // down: K=4096 N=2048, fused bias, fp32 scatter to output
    moe_gemm<FDIM, HDIM, true><<<dim3(HDIM / 128, TOKENS / 128, 2), 256, 0, stream>>>(
        Hb, Wb, b0b, b1b, nullptr, out, n0, perm);
}

// Round 3
// 679.985 us; speedup vs baseline: 1.1332x; 1.1332x over previous
//
#include <hip/hip_runtime.h>
#include <hip/hip_bf16.h>
#include <math.h>

// ---------------------------------------------------------------------------
// ToyMoE: top-1 routed 2-expert MLP. H=2048, tokens = 8192.
//   R2: 770us. GEMMs 2x243us @565TF (MfmaUtil 24%), aux ~284us.
//   R3: BK=64 K-loop (32 MFMA per barrier-pair, halve vmcnt(0) drains);
//       fused gate+gather (one x pass, batched atomics).
// ---------------------------------------------------------------------------

#define HDIM   2048
#define TOKENS 8192
#define FDIM   4096   // 2*H

typedef __bf16 bf16x8 __attribute__((ext_vector_type(8)));
typedef __bf16 bf16x4 __attribute__((ext_vector_type(4)));
typedef float  f32x4  __attribute__((ext_vector_type(4)));

// workspace layout (bytes)
#define CNT_OFF  0           // n0 (int), n1 (int)
#define PERM_OFF 256         // int[8192]
#define XG_OFF   65536       // bf16 [8192][2048]   = 33554432 B
#define WA_OFF   33619968    // bf16 [2][4096][2048] = 33554432 B
#define WB_OFF   67174400    // bf16 [2][2048][4096] = 33554432 B
#define HB_OFF   100728832   // bf16 [8192][4096]    = 67108864 B

typedef __attribute__((address_space(1))) const unsigned int as1_u32;
typedef __attribute__((address_space(3))) unsigned int       as3_u32;

__device__ __forceinline__ void gl2lds16(const void* g, void* l) {
    __builtin_amdgcn_global_load_lds((as1_u32*)g, (as3_u32*)l, 16, 0, 0);
}

// ------- fused gate(fp64 argmax) + routed gather + bf16 cast ---------------
// block = 256 threads = 4 waves; wave w gates+copies token blockIdx.x*4+w.
__global__ void moe_gate_gather(const float* __restrict__ x, const float* __restrict__ Wg,
                                int* __restrict__ n0, int* __restrict__ n1,
                                int* __restrict__ perm, __bf16* __restrict__ Xg) {
    __shared__ int sel[4];
    __shared__ int pos[4];
    const int tid  = threadIdx.x;
    const int wid  = tid >> 6;
    const int lane = tid & 63;
    const int token = blockIdx.x * 4 + wid;
    const float* xr = x + (size_t)token * HDIM;

    float4 xv[8];
    double s0 = 0.0, s1 = 0.0;
#pragma unroll
    for (int j = 0; j < 8; j++) {
        const int idx = j * 256 + lane * 4;
        xv[j] = *reinterpret_cast<const float4*>(xr + idx);
        float4 g0 = *reinterpret_cast<const float4*>(Wg + idx);
        float4 g1 = *reinterpret_cast<const float4*>(Wg + HDIM + idx);
        s0 += (double)xv[j].x * g0.x + (double)xv[j].y * g0.y
            + (double)xv[j].z * g0.z + (double)xv[j].w * g0.w;
        s1 += (double)xv[j].x * g1.x + (double)xv[j].y * g1.y
            + (double)xv[j].z * g1.z + (double)xv[j].w * g1.w;
    }
#pragma unroll
    for (int off = 32; off > 0; off >>= 1) {
        s0 += __shfl_down(s0, off);
        s1 += __shfl_down(s1, off);
    }
    if (lane == 0) sel[wid] = (s1 > s0) ? 1 : 0;   // softmax monotone; ties -> e0
    __syncthreads();
    if (tid == 0) {
        int c0 = (sel[0] == 0) + (sel[1] == 0) + (sel[2] == 0) + (sel[3] == 0);
        int p0 = c0 ? atomicAdd(n0, c0) : 0;
        int p1 = (c0 < 4) ? atomicAdd(n1, 4 - c0) : 0;
#pragma unroll
        for (int w = 0; w < 4; w++) {
            if (sel[w] == 0) pos[w] = p0++;
            else             pos[w] = TOKENS - 1 - (p1++);
        }
    }
    __syncthreads();
    const int dst = pos[wid];
    if (lane == 0) perm[dst] = token;
    __bf16* dr = Xg + (size_t)dst * HDIM;
#pragma unroll
    for (int j = 0; j < 8; j++) {
        const int idx = j * 256 + lane * 4;
        bf16x4 v;
        v[0] = (__bf16)xv[j].x; v[1] = (__bf16)xv[j].y;
        v[2] = (__bf16)xv[j].z; v[3] = (__bf16)xv[j].w;
        *reinterpret_cast<bf16x4*>(dr + idx) = v;
    }
}

// ---------------- cast the 4 expert weight matrices to bf16 -----------------
__global__ void moe_cast_w(const float* __restrict__ W0a, const float* __restrict__ W1a,
                           const float* __restrict__ W0b, const float* __restrict__ W1b,
                           __bf16* __restrict__ Wa, __bf16* __restrict__ Wb) {
    const int slice = blockIdx.y;
    const float* src;
    __bf16* dst;
    const size_t MS = (size_t)FDIM * HDIM;
    if      (slice == 0) { src = W0a; dst = Wa; }
    else if (slice == 1) { src = W1a; dst = Wa + MS; }
    else if (slice == 2) { src = W0b; dst = Wb; }
    else                 { src = W1b; dst = Wb + MS; }
    const size_t idx = ((size_t)blockIdx.x * 256 + threadIdx.x) * 8;
    float4 a = *reinterpret_cast<const float4*>(src + idx);
    float4 b = *reinterpret_cast<const float4*>(src + idx + 4);
    bf16x8 v;
    v[0] = (__bf16)a.x; v[1] = (__bf16)a.y; v[2] = (__bf16)a.z; v[3] = (__bf16)a.w;
    v[4] = (__bf16)b.x; v[5] = (__bf16)b.y; v[6] = (__bf16)b.z; v[7] = (__bf16)b.w;
    *reinterpret_cast<bf16x8*>(dst + idx) = v;
}

// ---------------- MFMA GEMM, 128x128 tile, BK=64 ---------------------------
// A:[8192][KDIM] bf16, Bw:[2][NDIM][KDIM] bf16 (K-contiguous, B^T GEMM)
// DOWN=false: out = act(A*B^T + bias) -> Hb bf16; DOWN=true: fp32 scatter.
template <int KDIM, int NDIM, bool DOWN>
__global__ void moe_gemm(const __bf16* __restrict__ A, const __bf16* __restrict__ Bw,
                         const float* __restrict__ bias0, const float* __restrict__ bias1,
                         __bf16* __restrict__ Hb, float* __restrict__ Out,
                         const int* __restrict__ n0_ptr, const int* __restrict__ perm) {
    const int e  = blockIdx.z;
    const int n0 = *n0_ptr;
    const int row_lo = e ? n0 : 0;
    const int row_hi = e ? TOKENS : n0;
    const int bm = blockIdx.y * 128;
    if (bm >= row_hi || bm + 128 <= row_lo) return;
    const int bn = blockIdx.x * 128;

    __shared__ __bf16 As[128 * 64];   // 16 KB
    __shared__ __bf16 Bs[128 * 64];   // 16 KB

    const int tid  = threadIdx.x;
    const int wid  = tid >> 6;
    const int lane = tid & 63;

    const __bf16* Be   = Bw + (size_t)e * NDIM * KDIM;
    const float*  bias = e ? bias1 : bias0;

    // staging (BK=64): one gl2lds16 covers 8 rows x 64 cols (lane l ->
    // row l/8, col (l%8)*8). Wave w stages rows [w*32, w*32+32) in 4 chunks.
    const int srow = wid * 32 + (lane >> 3);
    const int skol = (lane & 7) * 8;
    const __bf16* gA = A  + (size_t)(bm + srow) * KDIM + skol;
    const __bf16* gB = Be + (size_t)(bn + srow) * KDIM + skol;
    __bf16* lA = &As[(wid * 32) * 64];
    __bf16* lB = &Bs[(wid * 32) * 64];

    const int wrow = (wid >> 1) * 64;
    const int wcol = (wid & 1) * 64;
    const int rm = lane & 15;
    const int q8 = (lane >> 4) * 8;

    f32x4 acc[4][4] = {};

    for (int kt = 0; kt < KDIM; kt += 64) {
#pragma unroll
        for (int c = 0; c < 4; c++) {
            gl2lds16(gA + (size_t)(c * 8) * KDIM + kt, lA + c * 8 * 64);
            gl2lds16(gB + (size_t)(c * 8) * KDIM + kt, lB + c * 8 * 64);
        }
        __syncthreads();

        bf16x8 aF[2][4], bF[2][4];
#pragma unroll
        for (int h = 0; h < 2; h++) {
#pragma unroll
            for (int i = 0; i < 4; i++) {
                aF[h][i] = *reinterpret_cast<const bf16x8*>(&As[(wrow + i * 16 + rm) * 64 + h * 32 + q8]);
                bF[h][i] = *reinterpret_cast<const bf16x8*>(&Bs[(wcol + i * 16 + rm) * 64 + h * 32 + q8]);
            }
        }
#pragma unroll
        for (int h = 0; h < 2; h++)
#pragma unroll
            for (int i = 0; i < 4; i++)
#pragma unroll
                for (int j = 0; j < 4; j++)
                    acc[i][j] = __builtin_amdgcn_mfma_f32_16x16x32_bf16(aF[h][i], bF[h][j], acc[i][j], 0, 0, 0);
        __syncthreads();
    }

    // epilogue. C/D layout: col = lane&15, row = (lane>>4)*4 + reg  [m89/m91]
    const int q4 = (lane >> 4) * 4;
#pragma unroll
    for (int j = 0; j < 4; j++) {
        const int col = bn + wcol + j * 16 + rm;
        const float bv = bias[col];
#pragma unroll
        for (int i = 0; i < 4; i++) {
            const int rbase = bm + wrow + i * 16 + q4;
#pragma unroll
            for (int r = 0; r < 4; r++) {
                const int row = rbase + r;
                if (row >= row_lo && row < row_hi) {
                    float v = acc[i][j][r] + bv;
                    if (!DOWN) {
                        if (e == 0) v = 0.5f * v * (1.0f + erff(v * 0.70710678118654752f));
                        else        v = v > 0.0f ? v : 0.0f;
                        Hb[(size_t)row * NDIM + col] = (__bf16)v;
                    } else {
                        Out[(size_t)perm[row] * HDIM + col] = v;
                    }
                }
            }
        }
    }
}

extern "C" void kernel_launch(void* const* d_in, const int* in_sizes, int n_in,
                              void* d_out, int out_size, void* d_ws, size_t ws_size,
                              hipStream_t stream) {
    const float* x   = (const float*)d_in[0];
    const float* Wg  = (const float*)d_in[1];
    const float* W0a = (const float*)d_in[2];
    const float* b0a = (const float*)d_in[3];
    const float* W0b = (const float*)d_in[4];
    const float* b0b = (const float*)d_in[5];
    const float* W1a = (const float*)d_in[6];
    const float* b1a = (const float*)d_in[7];
    const float* W1b = (const float*)d_in[8];
    const float* b1b = (const float*)d_in[9];
    float* out = (float*)d_out;

    char* w = (char*)d_ws;
    int* n0   = (int*)(w + CNT_OFF);
    int* n1   = n0 + 1;
    int* perm = (int*)(w + PERM_OFF);
    __bf16* Xg = (__bf16*)(w + XG_OFF);
    __bf16* Wa = (__bf16*)(w + WA_OFF);
    __bf16* Wb = (__bf16*)(w + WB_OFF);
    __bf16* Hb = (__bf16*)(w + HB_OFF);

    (void)hipMemsetAsync(w, 0, 256, stream);
    moe_gate_gather<<<TOKENS / 4, 256, 0, stream>>>(x, Wg, n0, n1, perm, Xg);
    moe_cast_w<<<dim3(4096, 4), 256, 0, stream>>>(W0a, W1a, W0b, W1b, Wa, Wb);
    moe_gemm<HDIM, FDIM, false><<<dim3(FDIM / 128, TOKENS / 128, 2), 256, 0, stream>>>(
        Xg, Wa, b0a, b1a, Hb, nullptr, n0, perm);
    moe_gemm<FDIM, HDIM, true><<<dim3(HDIM / 128, TOKENS / 128, 2), 256, 0, stream>>>(
        Hb, Wb, b0b, b1b, nullptr, out, n0, perm);
}

// Round 4
// 603.724 us; speedup vs baseline: 1.2764x; 1.1263x over previous
//
#include <hip/hip_runtime.h>
#include <hip/hip_bf16.h>
#include <math.h>

// ---------------------------------------------------------------------------
// ToyMoE: top-1 routed 2-expert MLP. H=2048, tokens = 8192.
//   R2: 770us. GEMMs 2x243us @565TF, conflicts 1.7e7.
//   R3: 680us. BK=64: GEMMs 2x228us, but conflicts tripled to 5.1e7 --
//       row stride 128B puts every rm-group on one 4-bank column (8-way).
//   R4: XOR-swizzled LDS layout: stage chunk (c^(r&7)) via per-lane source
//       address (global_load_lds dest is fixed contiguous), read back at
//       (q^(R&7)). Each 8-lane group covers all 32 banks once -> 0 conflicts.
// ---------------------------------------------------------------------------

#define HDIM   2048
#define TOKENS 8192
#define FDIM   4096   // 2*H

typedef __bf16 bf16x8 __attribute__((ext_vector_type(8)));
typedef __bf16 bf16x4 __attribute__((ext_vector_type(4)));
typedef float  f32x4  __attribute__((ext_vector_type(4)));

// workspace layout (bytes)
#define CNT_OFF  0           // n0 (int), n1 (int)
#define PERM_OFF 256         // int[8192]
#define XG_OFF   65536       // bf16 [8192][2048]   = 33554432 B
#define WA_OFF   33619968    // bf16 [2][4096][2048] = 33554432 B
#define WB_OFF   67174400    // bf16 [2][2048][4096] = 33554432 B
#define HB_OFF   100728832   // bf16 [8192][4096]    = 67108864 B

typedef __attribute__((address_space(1))) const unsigned int as1_u32;
typedef __attribute__((address_space(3))) unsigned int       as3_u32;

__device__ __forceinline__ void gl2lds16(const void* g, void* l) {
    __builtin_amdgcn_global_load_lds((as1_u32*)g, (as3_u32*)l, 16, 0, 0);
}

// ------- fused gate(fp64 argmax) + routed gather + bf16 cast ---------------
// block = 256 threads = 4 waves; wave w gates+copies token blockIdx.x*4+w.
__global__ void moe_gate_gather(const float* __restrict__ x, const float* __restrict__ Wg,
                                int* __restrict__ n0, int* __restrict__ n1,
                                int* __restrict__ perm, __bf16* __restrict__ Xg) {
    __shared__ int sel[4];
    __shared__ int pos[4];
    const int tid  = threadIdx.x;
    const int wid  = tid >> 6;
    const int lane = tid & 63;
    const int token = blockIdx.x * 4 + wid;
    const float* xr = x + (size_t)token * HDIM;

    float4 xv[8];
    double s0 = 0.0, s1 = 0.0;
#pragma unroll
    for (int j = 0; j < 8; j++) {
        const int idx = j * 256 + lane * 4;
        xv[j] = *reinterpret_cast<const float4*>(xr + idx);
        float4 g0 = *reinterpret_cast<const float4*>(Wg + idx);
        float4 g1 = *reinterpret_cast<const float4*>(Wg + HDIM + idx);
        s0 += (double)xv[j].x * g0.x + (double)xv[j].y * g0.y
            + (double)xv[j].z * g0.z + (double)xv[j].w * g0.w;
        s1 += (double)xv[j].x * g1.x + (double)xv[j].y * g1.y
            + (double)xv[j].z * g1.z + (double)xv[j].w * g1.w;
    }
#pragma unroll
    for (int off = 32; off > 0; off >>= 1) {
        s0 += __shfl_down(s0, off);
        s1 += __shfl_down(s1, off);
    }
    if (lane == 0) sel[wid] = (s1 > s0) ? 1 : 0;   // softmax monotone; ties -> e0
    __syncthreads();
    if (tid == 0) {
        int c0 = (sel[0] == 0) + (sel[1] == 0) + (sel[2] == 0) + (sel[3] == 0);
        int p0 = c0 ? atomicAdd(n0, c0) : 0;
        int p1 = (c0 < 4) ? atomicAdd(n1, 4 - c0) : 0;
#pragma unroll
        for (int w = 0; w < 4; w++) {
            if (sel[w] == 0) pos[w] = p0++;
            else             pos[w] = TOKENS - 1 - (p1++);
        }
    }
    __syncthreads();
    const int dst = pos[wid];
    if (lane == 0) perm[dst] = token;
    __bf16* dr = Xg + (size_t)dst * HDIM;
#pragma unroll
    for (int j = 0; j < 8; j++) {
        const int idx = j * 256 + lane * 4;
        bf16x4 v;
        v[0] = (__bf16)xv[j].x; v[1] = (__bf16)xv[j].y;
        v[2] = (__bf16)xv[j].z; v[3] = (__bf16)xv[j].w;
        *reinterpret_cast<bf16x4*>(dr + idx) = v;
    }
}

// ---------------- cast the 4 expert weight matrices to bf16 -----------------
__global__ void moe_cast_w(const float* __restrict__ W0a, const float* __restrict__ W1a,
                           const float* __restrict__ W0b, const float* __restrict__ W1b,
                           __bf16* __restrict__ Wa, __bf16* __restrict__ Wb) {
    const int slice = blockIdx.y;
    const float* src;
    __bf16* dst;
    const size_t MS = (size_t)FDIM * HDIM;
    if      (slice == 0) { src = W0a; dst = Wa; }
    else if (slice == 1) { src = W1a; dst = Wa + MS; }
    else if (slice == 2) { src = W0b; dst = Wb; }
    else                 { src = W1b; dst = Wb + MS; }
    const size_t idx = ((size_t)blockIdx.x * 256 + threadIdx.x) * 8;
    float4 a = *reinterpret_cast<const float4*>(src + idx);
    float4 b = *reinterpret_cast<const float4*>(src + idx + 4);
    bf16x8 v;
    v[0] = (__bf16)a.x; v[1] = (__bf16)a.y; v[2] = (__bf16)a.z; v[3] = (__bf16)a.w;
    v[4] = (__bf16)b.x; v[5] = (__bf16)b.y; v[6] = (__bf16)b.z; v[7] = (__bf16)b.w;
    *reinterpret_cast<bf16x8*>(dst + idx) = v;
}

// ---------------- MFMA GEMM, 128x128 tile, BK=64, XOR-swizzled LDS ---------
// A:[8192][KDIM] bf16, Bw:[2][NDIM][KDIM] bf16 (K-contiguous, B^T GEMM)
// DOWN=false: out = act(A*B^T + bias) -> Hb bf16; DOWN=true: fp32 scatter.
// LDS layout: slot (row r, 16B-chunk c') holds global (r, c' ^ (r&7)).
template <int KDIM, int NDIM, bool DOWN>
__global__ void moe_gemm(const __bf16* __restrict__ A, const __bf16* __restrict__ Bw,
                         const float* __restrict__ bias0, const float* __restrict__ bias1,
                         __bf16* __restrict__ Hb, float* __restrict__ Out,
                         const int* __restrict__ n0_ptr, const int* __restrict__ perm) {
    const int e  = blockIdx.z;
    const int n0 = *n0_ptr;
    const int row_lo = e ? n0 : 0;
    const int row_hi = e ? TOKENS : n0;
    const int bm = blockIdx.y * 128;
    if (bm >= row_hi || bm + 128 <= row_lo) return;
    const int bn = blockIdx.x * 128;

    __shared__ __bf16 As[128 * 64];   // 16 KB
    __shared__ __bf16 Bs[128 * 64];   // 16 KB

    const int tid  = threadIdx.x;
    const int wid  = tid >> 6;
    const int lane = tid & 63;

    const __bf16* Be   = Bw + (size_t)e * NDIM * KDIM;
    const float*  bias = e ? bias1 : bias0;

    // staging (BK=64): one gl2lds16 covers 8 rows x 128B. Lane l -> LDS slot
    // (row l>>3, chunk l&7); source chunk is XOR-swizzled: (l&7)^(l>>3).
    // Wave w stages rows [w*32, w*32+32) in 4 chunks of 8 rows.
    const int srow = wid * 32 + (lane >> 3);
    const int skol = (((lane & 7) ^ (lane >> 3)) * 8);   // swizzled source col
    const __bf16* gA = A  + (size_t)(bm + srow) * KDIM + skol;
    const __bf16* gB = Be + (size_t)(bn + srow) * KDIM + skol;
    __bf16* lA = &As[(wid * 32) * 64];
    __bf16* lB = &Bs[(wid * 32) * 64];

    const int wrow = (wid >> 1) * 64;
    const int wcol = (wid & 1) * 64;
    const int rm = lane & 15;
    const int g  = lane >> 4;        // 0..3
    const int rsw = rm & 7;          // read-side swizzle key (R&7)

    f32x4 acc[4][4] = {};

    for (int kt = 0; kt < KDIM; kt += 64) {
#pragma unroll
        for (int c = 0; c < 4; c++) {
            gl2lds16(gA + (size_t)(c * 8) * KDIM + kt, lA + c * 8 * 64);
            gl2lds16(gB + (size_t)(c * 8) * KDIM + kt, lB + c * 8 * 64);
        }
        __syncthreads();

        // fragment read: global chunk q = h*4+g at row R -> LDS chunk q^(R&7)
        bf16x8 aF[2][4], bF[2][4];
#pragma unroll
        for (int h = 0; h < 2; h++) {
            const int csw = ((h * 4 + g) ^ rsw) * 8;
#pragma unroll
            for (int i = 0; i < 4; i++) {
                aF[h][i] = *reinterpret_cast<const bf16x8*>(&As[(wrow + i * 16 + rm) * 64 + csw]);
                bF[h][i] = *reinterpret_cast<const bf16x8*>(&Bs[(wcol + i * 16 + rm) * 64 + csw]);
            }
        }
#pragma unroll
        for (int h = 0; h < 2; h++)
#pragma unroll
            for (int i = 0; i < 4; i++)
#pragma unroll
                for (int j = 0; j < 4; j++)
                    acc[i][j] = __builtin_amdgcn_mfma_f32_16x16x32_bf16(aF[h][i], bF[h][j], acc[i][j], 0, 0, 0);
        __syncthreads();
    }

    // epilogue. C/D layout: col = lane&15, row = (lane>>4)*4 + reg  [m89/m91]
    const int q4 = g * 4;
#pragma unroll
    for (int j = 0; j < 4; j++) {
        const int col = bn + wcol + j * 16 + rm;
        const float bv = bias[col];
#pragma unroll
        for (int i = 0; i < 4; i++) {
            const int rbase = bm + wrow + i * 16 + q4;
#pragma unroll
            for (int r = 0; r < 4; r++) {
                const int row = rbase + r;
                if (row >= row_lo && row < row_hi) {
                    float v = acc[i][j][r] + bv;
                    if (!DOWN) {
                        if (e == 0) v = 0.5f * v * (1.0f + erff(v * 0.70710678118654752f));
                        else        v = v > 0.0f ? v : 0.0f;
                        Hb[(size_t)row * NDIM + col] = (__bf16)v;
                    } else {
                        Out[(size_t)perm[row] * HDIM + col] = v;
                    }
                }
            }
        }
    }
}

extern "C" void kernel_launch(void* const* d_in, const int* in_sizes, int n_in,
                              void* d_out, int out_size, void* d_ws, size_t ws_size,
                              hipStream_t stream) {
    const float* x   = (const float*)d_in[0];
    const float* Wg  = (const float*)d_in[1];
    const float* W0a = (const float*)d_in[2];
    const float* b0a = (const float*)d_in[3];
    const float* W0b = (const float*)d_in[4];
    const float* b0b = (const float*)d_in[5];
    const float* W1a = (const float*)d_in[6];
    const float* b1a = (const float*)d_in[7];
    const float* W1b = (const float*)d_in[8];
    const float* b1b = (const float*)d_in[9];
    float* out = (float*)d_out;

    char* w = (char*)d_ws;
    int* n0   = (int*)(w + CNT_OFF);
    int* n1   = n0 + 1;
    int* perm = (int*)(w + PERM_OFF);
    __bf16* Xg = (__bf16*)(w + XG_OFF);
    __bf16* Wa = (__bf16*)(w + WA_OFF);
    __bf16* Wb = (__bf16*)(w + WB_OFF);
    __bf16* Hb = (__bf16*)(w + HB_OFF);

    (void)hipMemsetAsync(w, 0, 256, stream);
    moe_gate_gather<<<TOKENS / 4, 256, 0, stream>>>(x, Wg, n0, n1, perm, Xg);
    moe_cast_w<<<dim3(4096, 4), 256, 0, stream>>>(W0a, W1a, W0b, W1b, Wa, Wb);
    moe_gemm<HDIM, FDIM, false><<<dim3(FDIM / 128, TOKENS / 128, 2), 256, 0, stream>>>(
        Xg, Wa, b0a, b1a, Hb, nullptr, n0, perm);
    moe_gemm<FDIM, HDIM, true><<<dim3(HDIM / 128, TOKENS / 128, 2), 256, 0, stream>>>(
        Hb, Wb, b0b, b1b, nullptr, out, n0, perm);
}